// Round 1
// baseline (270.696 us; speedup 1.0000x reference)
//
#include <hip/hip_runtime.h>
#include <hip/hip_bf16.h>

// tRNN fused kernel: embedding -> 6 tree-composition levels (MFMA bf16) -> cpr -> softmax
// B=8192, SIDES=2, L=64, V=10000, D=128, C=128, R=7

typedef __attribute__((ext_vector_type(8))) short bf16x8;
typedef __attribute__((ext_vector_type(4))) float f32x4;

#define G 4  // trees per block (= 2 batch rows, both sides)

__device__ __forceinline__ ushort f2b(float x) {
  __hip_bfloat16 h = __float2bfloat16(x);
  union { __hip_bfloat16 h; ushort u; } cv; cv.h = h; return cv.u;
}
__device__ __forceinline__ float b2f(ushort u) {
  union { ushort u; __hip_bfloat16 h; } cv; cv.u = u; return __bfloat162float(cv.h);
}
__device__ __forceinline__ float fast_tanh(float x) {
  x = fminf(fmaxf(x, -15.f), 15.f);
  float e = __expf(2.f * x);
  return (e - 1.f) / (e + 1.f);
}

// One tree level: NODES = output nodes per tree. Inputs: rows [0, 2*NODES) of each
// tree's h (bf16, swizzled). Outputs: rows [0, NODES). Two barriers: all-read, all-write.
template<int NODES>
__device__ __forceinline__ void level_step(ushort* h, const bf16x8 (&A)[2][8],
                                           const float (&bias)[2][4],
                                           int lane, int wv) {
  constexpr int NTOT = G * NODES;            // total output nodes in block
  constexpr int NT = (NTOT + 15) / 16;       // N-tiles of 16
  const int l15 = lane & 15, lh = lane >> 4;

  f32x4 acc[NT][2];
  const f32x4 zero = {0.f, 0.f, 0.f, 0.f};
#pragma unroll
  for (int nt = 0; nt < NT; ++nt) { acc[nt][0] = zero; acc[nt][1] = zero; }

#pragma unroll
  for (int nt = 0; nt < NT; ++nt) {
    int node = nt * 16 + l15;
    if constexpr (NTOT < 16) { if (node >= NTOT) node = 0; }  // clamp (reads garbage-safe)
    const int tree = node / NODES;
    const int i    = node % NODES;
    const int rbase = tree * 64;
    bf16x8 bf[8];
#pragma unroll
    for (int kt = 0; kt < 8; ++kt) {
      const int child = 2 * i + (kt >> 2);            // kt 0..3 -> left child, 4..7 -> right
      const int kk    = (kt & 3) * 32 + lh * 8;       // k within child's 128
      const int byteoff = (rbase + child) * 256 + ((kk * 2) ^ ((i & 7) << 4));
      bf[kt] = *(const bf16x8*)((const char*)h + byteoff);
    }
#pragma unroll
    for (int kt = 0; kt < 8; ++kt) {
      acc[nt][0] = __builtin_amdgcn_mfma_f32_16x16x32_bf16(A[0][kt], bf[kt], acc[nt][0], 0, 0, 0);
      acc[nt][1] = __builtin_amdgcn_mfma_f32_16x16x32_bf16(A[1][kt], bf[kt], acc[nt][1], 0, 0, 0);
    }
  }
  __syncthreads();   // all reads of this level complete

#pragma unroll
  for (int nt = 0; nt < NT; ++nt) {
    const int node = nt * 16 + l15;
    bool valid = true;
    int node_c = node;
    if constexpr (NTOT < 16) { valid = node < NTOT; if (!valid) node_c = 0; }
    const int tree = node_c / NODES;
    const int i    = node_c % NODES;
    char* rowp = (char*)h + (tree * 64 + i) * 256;
    const int key = ((i >> 1) & 7) << 4;
#pragma unroll
    for (int mt = 0; mt < 2; ++mt) {
      const int d0 = wv * 32 + mt * 16 + lh * 4;
      ushort4 pk;
      pk.x = f2b(fast_tanh(acc[nt][mt][0] + bias[mt][0]));
      pk.y = f2b(fast_tanh(acc[nt][mt][1] + bias[mt][1]));
      pk.z = f2b(fast_tanh(acc[nt][mt][2] + bias[mt][2]));
      pk.w = f2b(fast_tanh(acc[nt][mt][3] + bias[mt][3]));
      if (valid) *(ushort4*)(rowp + ((d0 * 2) ^ key)) = pk;
    }
  }
  __syncthreads();   // all writes complete before next level reads
}

__global__ __launch_bounds__(256, 2)
void trnn_kernel(const int* __restrict__ tokens, const float* __restrict__ voc_w,
                 const float* __restrict__ voc_b, const float* __restrict__ cps_w,
                 const float* __restrict__ cps_b, const float* __restrict__ cpr_w,
                 const float* __restrict__ cpr_b, const float* __restrict__ sm_w,
                 const float* __restrict__ sm_b, float* __restrict__ out) {
  __shared__ ushort h[G * 64 * 128];   // 64 KB: 4 trees x 64 rows x 128 bf16, swizzled
  __shared__ float zbuf[2 * 128];

  const int tid  = threadIdx.x;
  const int lane = tid & 63;
  const int wv   = tid >> 6;
  const int b0   = blockIdx.x * 2;

  // ---- load cps weights as A-fragments (wave wv owns d-rows [wv*32, wv*32+32)) ----
  bf16x8 A[2][8];
  float  bias[2][4];
  {
    const int l15 = lane & 15, lh = lane >> 4;
#pragma unroll
    for (int mt = 0; mt < 2; ++mt) {
      const int d = wv * 32 + mt * 16 + l15;
#pragma unroll
      for (int kt = 0; kt < 8; ++kt) {
        const int k = kt * 32 + lh * 8;
        const float* p = cps_w + d * 256 + k;
        float4 lo = *(const float4*)p;
        float4 hi = *(const float4*)(p + 4);
        bf16x8 f;
        f[0] = f2b(lo.x); f[1] = f2b(lo.y); f[2] = f2b(lo.z); f[3] = f2b(lo.w);
        f[4] = f2b(hi.x); f[5] = f2b(hi.y); f[6] = f2b(hi.z); f[7] = f2b(hi.w);
        A[mt][kt] = f;
      }
#pragma unroll
      for (int r = 0; r < 4; ++r)
        bias[mt][r] = cps_b[wv * 32 + mt * 16 + lh * 4 + r];
    }
  }

  // ---- embedding: one thread per (tree, leaf) row ----
  {
    const int tree = tid >> 6, leaf = tid & 63;
    const int tok  = tokens[b0 * 128 + tree * 64 + leaf];
    const float* vw = voc_w + tok * 128;
    const int key = ((leaf >> 1) & 7) << 4;
    char* rowp = (char*)h + tree * 16384 + leaf * 256;
#pragma unroll 8
    for (int c4 = 0; c4 < 32; ++c4) {
      float4 v  = *(const float4*)(vw + c4 * 4);
      float4 bb = *(const float4*)(voc_b + c4 * 4);
      ushort4 pk;
      pk.x = f2b(v.x + bb.x); pk.y = f2b(v.y + bb.y);
      pk.z = f2b(v.z + bb.z); pk.w = f2b(v.w + bb.w);
      *(ushort4*)(rowp + ((c4 * 8) ^ key)) = pk;
    }
  }
  __syncthreads();

  // ---- 6 composition levels: 64 leaves -> 1 root per tree ----
  level_step<32>(h, A, bias, lane, wv);
  level_step<16>(h, A, bias, lane, wv);
  level_step<8>(h, A, bias, lane, wv);
  level_step<4 >(h, A, bias, lane, wv);
  level_step<2 >(h, A, bias, lane, wv);
  level_step<1 >(h, A, bias, lane, wv);

  // ---- cpr: z[r][c] = leaky(root_cat[r] . cpr_w[c] + cpr_b[c]), r=0,1 batch rows ----
  {
    const int r = tid >> 7, c = tid & 127;
    const ushort* rt0 = h + (2 * r) * 8192;       // tree 2r, row 0 (key=0: linear)
    const ushort* rt1 = h + (2 * r + 1) * 8192;   // tree 2r+1, row 0
    const float* wrow = cpr_w + c * 256;
    float acc = cpr_b[c];
#pragma unroll 8
    for (int k4 = 0; k4 < 32; ++k4) {
      float4 w = *(const float4*)(wrow + k4 * 4);
      ushort4 u = *(const ushort4*)(rt0 + k4 * 4);
      acc += b2f(u.x) * w.x + b2f(u.y) * w.y + b2f(u.z) * w.z + b2f(u.w) * w.w;
    }
#pragma unroll 8
    for (int k4 = 0; k4 < 32; ++k4) {
      float4 w = *(const float4*)(wrow + 128 + k4 * 4);
      ushort4 u = *(const ushort4*)(rt1 + k4 * 4);
      acc += b2f(u.x) * w.x + b2f(u.y) * w.y + b2f(u.z) * w.z + b2f(u.w) * w.w;
    }
    zbuf[r * 128 + c] = acc > 0.f ? acc : 0.01f * acc;
  }
  __syncthreads();

  // ---- softmax head: wave 0 -> batch row 0, wave 1 -> batch row 1 ----
  if (wv < 2) {
    const int r = wv;
    float p[7];
#pragma unroll
    for (int j = 0; j < 7; ++j) {
      p[j] = zbuf[r * 128 + lane]      * sm_w[j * 128 + lane]
           + zbuf[r * 128 + 64 + lane] * sm_w[j * 128 + 64 + lane];
    }
#pragma unroll
    for (int j = 0; j < 7; ++j) {
      float v = p[j];
#pragma unroll
      for (int off = 32; off >= 1; off >>= 1) v += __shfl_xor(v, off, 64);
      p[j] = v + sm_b[j];
    }
    float mx = p[0];
#pragma unroll
    for (int j = 1; j < 7; ++j) mx = fmaxf(mx, p[j]);
    float e[7], s = 0.f;
#pragma unroll
    for (int j = 0; j < 7; ++j) { e[j] = __expf(p[j] - mx); s += e[j]; }
    const float inv = 1.f / s;
    if (lane == 0) {
#pragma unroll
      for (int j = 0; j < 7; ++j) out[(b0 + r) * 7 + j] = e[j] * inv;
    }
  }
}

extern "C" void kernel_launch(void* const* d_in, const int* in_sizes, int n_in,
                              void* d_out, int out_size, void* d_ws, size_t ws_size,
                              hipStream_t stream) {
  const int*   tokens = (const int*)  d_in[0];
  const float* voc_w  = (const float*)d_in[1];
  const float* voc_b  = (const float*)d_in[2];
  const float* cps_w  = (const float*)d_in[3];
  const float* cps_b  = (const float*)d_in[4];
  const float* cpr_w  = (const float*)d_in[5];
  const float* cpr_b  = (const float*)d_in[6];
  const float* sm_w   = (const float*)d_in[7];
  const float* sm_b   = (const float*)d_in[8];

  const int Btot = in_sizes[0] / 128;   // 8192
  dim3 grid(Btot / 2), block(256);
  trnn_kernel<<<grid, block, 0, stream>>>(tokens, voc_w, voc_b, cps_w, cps_b,
                                          cpr_w, cpr_b, sm_w, sm_b, (float*)d_out);
}